// Round 5
// baseline (589.042 us; speedup 1.0000x reference)
//
#include <hip/hip_runtime.h>

// LightGCN, atomic-free CSR build (bucketed counting sort) + bf16 g-form layers.
//
// Build pipeline (no global atomics, no memset):
//   k_bucket_count   : 1024 blocks x disjoint edge ranges, LDS hist over
//                      node-buckets (1024 nodes each), dump bh[k][b].
//   k_scan_blocks    : per-bucket exclusive scan over the 1024 block counts
//                      (in-place in bh) + bucket totals.
//   k_bucket_scatter : re-stream edge ranges; SORT the block's entries by
//                      bucket in LDS (hist -> scan -> place w/ precomputed
//                      global dst), then stream out coalesced.
//   k_node_count     : 4*NB blocks (256-node sub-buckets): scan parent
//                      bucket entries, LDS 256-bin hist + float deg for the
//                      sub-range, 256-wide scan -> cnt/dinv/dsq/loffs +
//                      padded sub-bucket total ssum. (R3's one-1024-thread-
//                      block-per-bucket k_bucket_csr was 107us at 16.5%
//                      occupancy: 147 blocks can't fill 256 CUs.)
//   k_scan_sub       : 1 block: exclusive scan of 4*NB sub totals -> sbase.
//   k_csr_place      : 4*NB blocks: offs = sbase + loffs, zero-fill pads,
//                      re-scan parent entries with per-node LDS cursors ->
//                      final CSR {col, v}. Rows padded to 4-entry multiples
//                      ({col=0,w=0} no-op slots), 32B-aligned bases.
//
// g-form: g = dinv(*)e; s_r = sum v*g_c; g' = dinv_r^2 * s_r.
// k_final reconstructs acc = e0 + sum_l dsq*g_l (dsq = sqrt(deg)).
//
// k_layer (R2): GROUP-PER-ROW. 8 lanes per row (lane q holds dims 8q..8q+7
// as uint4), 8 rows per wave. No shuffles, no reduction epilogue. Inner
// loop: 2x dwordx4 csr loads + 4 independent 16B row gathers per 4
// neighbors, next csr block prefetched under the FMAs. Branch-free.

static inline size_t align_up(size_t x, size_t a) { return (x + a - 1) & ~(a - 1); }

#define BS_LOG 10        // bucket = 1024 nodes
#define NBA 160          // max buckets (N <= 163840); N = 150000 -> NB = 147
#define KB  1024         // edge-range blocks for count/scatter passes
#define ENT 4096         // staged entries per scatter block (2*CH <= 3908)

__device__ inline unsigned short f32_to_bf16(float f) {
    unsigned int u = __float_as_uint(f);
    unsigned int r = (u + 0x7FFFu + ((u >> 16) & 1u)) >> 16;   // RNE
    return (unsigned short)r;
}
__device__ inline float bf16_to_f32(unsigned short h) {
    return __uint_as_float(((unsigned int)h) << 16);
}
__device__ inline float bf16_lo(unsigned int d) {
    return __uint_as_float(d << 16);
}
__device__ inline float bf16_hi(unsigned int d) {
    return __uint_as_float(d & 0xFFFF0000u);
}

// 1024 blocks, block k owns edges [k*CH, min(E,(k+1)*CH)).
// LDS histogram over node-buckets (node>>10); dump bh[k*NBA + b] (coalesced).
__global__ __launch_bounds__(256) void k_bucket_count(
        const int* __restrict__ eu, const int* __restrict__ ei,
        int* __restrict__ bh, int U, int E, int NB, int CH) {
    __shared__ int hist[NBA];
    int k = blockIdx.x;
    int t = threadIdx.x;
    if (t < NBA) hist[t] = 0;
    __syncthreads();
    int lo = k * CH, hi = min(E, lo + CH);
    for (int i = lo + t; i < hi; i += 256) {
        int u  = eu[i];
        int it = ei[i] + U;
        atomicAdd(&hist[u >> BS_LOG], 1);
        atomicAdd(&hist[it >> BS_LOG], 1);
    }
    __syncthreads();
    if (t < NB) bh[k * NBA + t] = hist[t];
}

// One block per bucket b: exclusive scan (in place) of bh[k][b] over k=0..1023,
// total[b] = sum. 256 threads x 4 sequential elements each.
__global__ __launch_bounds__(256) void k_scan_blocks(
        int* __restrict__ bh, int* __restrict__ total, int NB) {
    __shared__ int s[256];
    int b = blockIdx.x;
    int t = threadIdx.x;
    int k0 = t * 4;
    int vals[4];
    int sum = 0;
    #pragma unroll
    for (int j = 0; j < 4; ++j) { vals[j] = bh[(k0 + j) * NBA + b]; sum += vals[j]; }
    s[t] = sum;
    __syncthreads();
    for (int d = 1; d < 256; d <<= 1) {
        int v = (t >= d) ? s[t - d] : 0;
        __syncthreads();
        s[t] += v;
        __syncthreads();
    }
    int run = s[t] - sum;            // exclusive base for this thread's chunk
    #pragma unroll
    for (int j = 0; j < 4; ++j) { int v = vals[j]; bh[(k0 + j) * NBA + b] = run; run += v; }
    if (t == 255) total[b] = run;
}

// LDS-sorted scatter. Entry: {(node&1023) | (col<<10), v_bits} (28 bits).
// Phase 1: local hist. Phase 2: scan -> segment starts + global-dst deltas.
// Phase 3: place entry + dst into LDS. Phase 4: stream out (consecutive
// threads -> consecutive slots of the same bucket segment -> coalesced).
__global__ __launch_bounds__(256) void k_bucket_scatter(
        const int* __restrict__ eu, const int* __restrict__ ei,
        const float* __restrict__ ev, const int* __restrict__ bh,
        int2* __restrict__ gb, int U, int E, int NB, int CH, int CAP) {
    __shared__ uint2 sent[ENT];
    __shared__ int   sdst[ENT];
    __shared__ int   lcur[NBA];
    __shared__ int   ldif[NBA];
    __shared__ int   sscan[256];
    __shared__ int   stot;
    int k = blockIdx.x;
    int t = threadIdx.x;
    if (t < NBA) lcur[t] = 0;
    __syncthreads();
    int lo = k * CH, hi = min(E, lo + CH);
    for (int i = lo + t; i < hi; i += 256) {
        int u  = eu[i];
        int it = ei[i] + U;
        atomicAdd(&lcur[u >> BS_LOG], 1);
        atomicAdd(&lcur[it >> BS_LOG], 1);
    }
    __syncthreads();
    int c = (t < NB) ? lcur[t] : 0;
    sscan[t] = c;
    __syncthreads();
    for (int d = 1; d < 256; d <<= 1) {
        int v = (t >= d) ? sscan[t - d] : 0;
        __syncthreads();
        sscan[t] += v;
        __syncthreads();
    }
    if (t < NB) {
        int st = sscan[t] - c;                    // local segment start
        lcur[t] = st;                             // reuse as cursor
        ldif[t] = t * CAP + bh[k * NBA + t] - st; // slot -> global dst delta
    }
    if (t == 255) stot = sscan[255];
    __syncthreads();
    for (int i = lo + t; i < hi; i += 256) {
        int u  = eu[i];
        int it = ei[i] + U;
        unsigned vb = __float_as_uint(ev[i]);
        int b1 = u >> BS_LOG;
        int s1 = atomicAdd(&lcur[b1], 1);
        sent[s1] = make_uint2((unsigned)((u & 1023) | (it << 10)), vb);
        sdst[s1] = ldif[b1] + s1;
        int b2 = it >> BS_LOG;
        int s2 = atomicAdd(&lcur[b2], 1);
        sent[s2] = make_uint2((unsigned)((it & 1023) | (u << 10)), vb);
        sdst[s2] = ldif[b2] + s2;
    }
    __syncthreads();
    int tot = stot;
    for (int i = t; i < tot; i += 256) {
        uint2 e = sent[i];
        gb[sdst[i]] = make_int2((int)e.x, (int)e.y);
    }
}

// One 256-thread block per 256-node SUB-bucket (blockIdx = b*4 + sub).
// Scan parent bucket entries, hist+deg for the sub-range only, 256-wide
// scan of align4(h) -> loffs (local, within sub-bucket), cnt/dinv/dsq,
// ssum[s] = padded sub-bucket total.
__global__ __launch_bounds__(256) void k_node_count(
        const int2* __restrict__ gb, const int* __restrict__ total,
        int* __restrict__ cnt, float* __restrict__ dinv, float* __restrict__ dsq,
        int* __restrict__ loffs, int* __restrict__ ssum,
        int N, int CAP) {
    __shared__ int   hist[256];
    __shared__ float degf[256];
    __shared__ int   scan[256];
    int s = blockIdx.x;
    int b = s >> 2, sub = s & 3;
    int t = threadIdx.x;
    int cb = min(total[b], CAP);
    const int2* gbb = gb + (size_t)b * CAP;
    hist[t] = 0;
    degf[t] = 0.f;
    __syncthreads();
    for (int i = t; i < cb; i += 256) {
        int2 e = gbb[i];
        int rl = e.x & 1023;
        if ((rl >> 8) == sub) {
            atomicAdd(&hist[rl & 255], 1);
            atomicAdd(&degf[rl & 255], __int_as_float(e.y));
        }
    }
    __syncthreads();
    int h = hist[t];
    int h4 = (h + 3) & ~3;
    scan[t] = h4;
    __syncthreads();
    for (int d = 1; d < 256; d <<= 1) {
        int v = (t >= d) ? scan[t - d] : 0;
        __syncthreads();
        scan[t] += v;
        __syncthreads();
    }
    int node = (b << BS_LOG) + (sub << 8) + t;
    if (node < N) {
        cnt[node]   = h;
        loffs[node] = scan[t] - h4;
        float sd = degf[t];
        bool pos = (sd > 0.0f);
        dinv[node] = pos ? rsqrtf(fmaxf(sd, 1e-12f)) : 0.0f;
        dsq[node]  = pos ? sqrtf(sd) : 0.0f;
    }
    if (t == 255) ssum[s] = scan[255];
}

// Single block: exclusive scan of NS (= 4*NB <= 640) sub totals -> sbase.
__global__ __launch_bounds__(1024) void k_scan_sub(
        const int* __restrict__ ssum, int* __restrict__ sbase, int NS) {
    __shared__ int s[1024];
    int t = threadIdx.x;
    int v = (t < NS) ? ssum[t] : 0;
    s[t] = v;
    __syncthreads();
    for (int d = 1; d < 1024; d <<= 1) {
        int x = (t >= d) ? s[t - d] : 0;
        __syncthreads();
        s[t] += x;
        __syncthreads();
    }
    if (t < NS) sbase[t] = s[t] - v;
}

// One 256-thread block per sub-bucket: offs = sbase + loffs, zero-fill pad
// slots, then re-scan parent entries with per-node LDS cursors -> final CSR.
__global__ __launch_bounds__(256) void k_csr_place(
        const int2* __restrict__ gb, const int* __restrict__ total,
        const int* __restrict__ sbase, const int* __restrict__ cnt,
        const int* __restrict__ loffs,
        int* __restrict__ offs, int2* __restrict__ csr, int N, int CAP) {
    __shared__ int lofs[256];
    __shared__ int cur[256];
    int s = blockIdx.x;
    int b = s >> 2, sub = s & 3;
    int t = threadIdx.x;
    int cb = min(total[b], CAP);
    int base = sbase[s];                 // multiple of 4 (sums of h4)
    const int2* gbb = gb + (size_t)b * CAP;
    int node = (b << BS_LOG) + (sub << 8) + t;
    int lo = 0, h = 0;
    if (node < N) { lo = loffs[node]; h = cnt[node]; }
    lofs[t] = lo;
    cur[t] = 0;
    if (node < N) {
        offs[node] = base + lo;
        int h4 = (h + 3) & ~3;
        for (int p = h; p < h4; ++p)     // zero-fill pad slots
            csr[base + lo + p] = make_int2(0, 0);
    }
    __syncthreads();
    for (int i = t; i < cb; i += 256) {
        int2 e = gbb[i];
        int rl = e.x & 1023;
        if ((rl >> 8) == sub) {
            int r = rl & 255;
            int tk = atomicAdd(&cur[r], 1);
            int col = (int)(((unsigned)e.x) >> 10);
            csr[base + lofs[r] + tk] = make_int2(col, e.y);
        }
    }
}

// g0 = bf16(dinv * concat(emb)). 4 elems/thread.
__global__ void k_init(const float4* __restrict__ emb_u, const float4* __restrict__ emb_i,
                       const float* __restrict__ dinv,
                       ushort4* __restrict__ g0, int U16, int N16) {
    int i = blockIdx.x * blockDim.x + threadIdx.x;
    if (i >= N16) return;
    float4 v = (i < U16) ? emb_u[i] : emb_i[i - U16];
    float d = dinv[i >> 4];
    ushort4 o;
    o.x = f32_to_bf16(v.x * d);
    o.y = f32_to_bf16(v.y * d);
    o.z = f32_to_bf16(v.z * d);
    o.w = f32_to_bf16(v.w * d);
    g0[i] = o;
}

// GROUP-PER-ROW: 8 lanes per row (q = lane&7 holds dims 8q..8q+7), 8 rows
// per wave. csr rows padded to 4-entry multiples, 32B-aligned -> inner loop
// is branch-free: 2x dwordx4 csr loads (broadcast within group) + 4
// independent 16B row gathers per 4 neighbors; next csr block prefetched
// under the FMAs. Pad entries {col=0,w=0} gather row 0 and add 0 (no-op).
__global__ __launch_bounds__(256) void k_layer(
        const uint4* __restrict__ gin, uint4* __restrict__ gout,
        const float* __restrict__ dinv,
        const int* __restrict__ offs, const int* __restrict__ cnt,
        const int2* __restrict__ csr, int N) {
    int gtid = blockIdx.x * blockDim.x + threadIdx.x;
    int row = gtid >> 3;
    unsigned q = threadIdx.x & 7;
    if (row >= N) return;
    int base = offs[row];
    int c = cnt[row];
    int nIter = (c + 3) >> 2;        // 4 neighbors per iteration

    float a0 = 0.f, a1 = 0.f, a2 = 0.f, a3 = 0.f;
    float a4 = 0.f, a5 = 0.f, a6 = 0.f, a7 = 0.f;

    const uint4* ep4 = (const uint4*)(csr + base);   // 32B-aligned
    uint4 E0 = make_uint4(0, 0, 0, 0), E1 = E0;
    if (nIter > 0) { E0 = ep4[0]; E1 = ep4[1]; }     // {c0,w0,c1,w1},{c2,w2,c3,w3}

    for (int i = 0; i < nIter; ++i) {
        uint4 G0 = gin[(E0.x << 3) | q];
        uint4 G1 = gin[(E0.z << 3) | q];
        uint4 G2 = gin[(E1.x << 3) | q];
        uint4 G3 = gin[(E1.z << 3) | q];
        // prefetch next csr block (reads <=32B past row end; slack allocated)
        uint4 P0 = ep4[2 * i + 2];
        uint4 P1 = ep4[2 * i + 3];
        float w0 = __uint_as_float(E0.y);
        float w1 = __uint_as_float(E0.w);
        float w2 = __uint_as_float(E1.y);
        float w3 = __uint_as_float(E1.w);
        a0 += w0 * bf16_lo(G0.x); a1 += w0 * bf16_hi(G0.x);
        a2 += w0 * bf16_lo(G0.y); a3 += w0 * bf16_hi(G0.y);
        a4 += w0 * bf16_lo(G0.z); a5 += w0 * bf16_hi(G0.z);
        a6 += w0 * bf16_lo(G0.w); a7 += w0 * bf16_hi(G0.w);
        a0 += w1 * bf16_lo(G1.x); a1 += w1 * bf16_hi(G1.x);
        a2 += w1 * bf16_lo(G1.y); a3 += w1 * bf16_hi(G1.y);
        a4 += w1 * bf16_lo(G1.z); a5 += w1 * bf16_hi(G1.z);
        a6 += w1 * bf16_lo(G1.w); a7 += w1 * bf16_hi(G1.w);
        a0 += w2 * bf16_lo(G2.x); a1 += w2 * bf16_hi(G2.x);
        a2 += w2 * bf16_lo(G2.y); a3 += w2 * bf16_hi(G2.y);
        a4 += w2 * bf16_lo(G2.z); a5 += w2 * bf16_hi(G2.z);
        a6 += w2 * bf16_lo(G2.w); a7 += w2 * bf16_hi(G2.w);
        a0 += w3 * bf16_lo(G3.x); a1 += w3 * bf16_hi(G3.x);
        a2 += w3 * bf16_lo(G3.y); a3 += w3 * bf16_hi(G3.y);
        a4 += w3 * bf16_lo(G3.z); a5 += w3 * bf16_hi(G3.z);
        a6 += w3 * bf16_lo(G3.w); a7 += w3 * bf16_hi(G3.w);
        E0 = P0; E1 = P1;
    }

    float dr = dinv[row];
    float d2 = dr * dr;
    uint4 o;
    o.x = (unsigned int)f32_to_bf16(d2 * a0) | ((unsigned int)f32_to_bf16(d2 * a1) << 16);
    o.y = (unsigned int)f32_to_bf16(d2 * a2) | ((unsigned int)f32_to_bf16(d2 * a3) << 16);
    o.z = (unsigned int)f32_to_bf16(d2 * a4) | ((unsigned int)f32_to_bf16(d2 * a5) << 16);
    o.w = (unsigned int)f32_to_bf16(d2 * a6) | ((unsigned int)f32_to_bf16(d2 * a7) << 16);
    gout[((unsigned)row << 3) | q] = o;
}

// out (float4 units): [Uf | Upass | If | Ipass]; Uf/If = (e0 + sum dsq*g_l)/25.
__global__ void k_final(const float4* __restrict__ emb_u, const float4* __restrict__ emb_i,
                        const ushort4* __restrict__ g1, const ushort4* __restrict__ g2,
                        const ushort4* __restrict__ g3, const ushort4* __restrict__ g4,
                        const float* __restrict__ dsq,
                        float4* __restrict__ out, int U16, int I16) {
    int i = blockIdx.x * blockDim.x + threadIdx.x;
    int total = 2 * U16 + 2 * I16;
    if (i >= total) return;
    const float s = 1.0f / 25.0f;
    float4 r;
    if (i < U16 || (i >= 2 * U16 && i < 2 * U16 + I16)) {
        int gi, node;
        float4 e0;
        if (i < U16) { gi = i; node = i >> 4; e0 = emb_u[i]; }
        else { int j = i - 2 * U16; gi = U16 + j; node = (U16 >> 4) + (j >> 4); e0 = emb_i[j]; }
        float d = dsq[node];
        ushort4 a = g1[gi], b = g2[gi], cc = g3[gi], dd = g4[gi];
        float gx = bf16_to_f32(a.x) + bf16_to_f32(b.x) + bf16_to_f32(cc.x) + bf16_to_f32(dd.x);
        float gy = bf16_to_f32(a.y) + bf16_to_f32(b.y) + bf16_to_f32(cc.y) + bf16_to_f32(dd.y);
        float gz = bf16_to_f32(a.z) + bf16_to_f32(b.z) + bf16_to_f32(cc.z) + bf16_to_f32(dd.z);
        float gw = bf16_to_f32(a.w) + bf16_to_f32(b.w) + bf16_to_f32(cc.w) + bf16_to_f32(dd.w);
        r = make_float4((e0.x + d * gx) * s, (e0.y + d * gy) * s,
                        (e0.z + d * gz) * s, (e0.w + d * gw) * s);
    } else if (i < 2 * U16) {
        r = emb_u[i - U16];
    } else {
        r = emb_i[i - 2 * U16 - I16];
    }
    out[i] = r;
}

extern "C" void kernel_launch(void* const* d_in, const int* in_sizes, int n_in,
                              void* d_out, int out_size, void* d_ws, size_t ws_size,
                              hipStream_t stream) {
    const float* emb_u = (const float*)d_in[0];
    const float* emb_i = (const float*)d_in[1];
    const int*   eu    = (const int*)d_in[2];
    const int*   ei    = (const int*)d_in[3];
    const float* ev    = (const float*)d_in[4];

    const int U = in_sizes[0] / 64;
    const int I = in_sizes[1] / 64;
    const int N = U + I;
    const int E = in_sizes[2];
    const int DE = 2 * E;

    const int NB = (N + 1023) >> BS_LOG;   // 147 buckets for N = 150000 (<= NBA)
    const int NS = NB * 4;                 // 588 sub-buckets (<= 640 <= 1024)
    const int CH = (E + KB - 1) / KB;      // edges per count/scatter block

    // ---- workspace carve ----
    char* base = (char*)d_ws;
    size_t off = 0;
    int*   offs  = (int*)  (base + off); off = align_up(off + (size_t)N * 4, 256);
    int*   cnt   = (int*)  (base + off); off = align_up(off + (size_t)N * 4, 256);
    float* dinv  = (float*)(base + off); off = align_up(off + (size_t)N * 4, 256);
    float* dsq   = (float*)(base + off); off = align_up(off + (size_t)N * 4, 256);
    int*   loffs = (int*)  (base + off); off = align_up(off + (size_t)N * 4, 256);
    int*   bh    = (int*)  (base + off); off = align_up(off + (size_t)NBA * KB * 4, 256);
    int*   total = (int*)  (base + off); off = align_up(off + (size_t)NBA * 4, 256);
    int*   ssum  = (int*)  (base + off); off = align_up(off + (size_t)NBA * 4 * 4, 256);
    int*   sbase = (int*)  (base + off); off = align_up(off + (size_t)NBA * 4 * 4, 256);
    // padded CSR: DE entries + per-node align4 slack (<3N) + prefetch slack
    int2*  csr   = (int2*) (base + off);
    off = align_up(off + ((size_t)DE + (size_t)N * 4 + 64) * 8, 256);
    unsigned short* g[5];
    for (int l = 0; l < 5; ++l) {
        g[l] = (unsigned short*)(base + off);
        off = align_up(off + (size_t)N * 64 * 2, 256);
    }
    (void)ws_size;

    // Bucket staging aliases g[1..4] (dead until layer 0 writes g[1]).
    int2* gb = (int2*)g[1];
    size_t gcap = (size_t)4 * N * 128;                 // bytes available at g[1]
    int CAP = (int)(gcap / ((size_t)NB * 8));          // per-bucket entry cap
    if (CAP > 65536) CAP = 65536;                      // ~2.3x max expected bucket load

    const int B = 256;
    k_bucket_count  <<<KB, B, 0, stream>>>(eu, ei, bh, U, E, NB, CH);
    k_scan_blocks   <<<NB, B, 0, stream>>>(bh, total, NB);
    k_bucket_scatter<<<KB, B, 0, stream>>>(eu, ei, ev, bh, gb, U, E, NB, CH, CAP);
    k_node_count    <<<NS, B, 0, stream>>>(gb, total, cnt, dinv, dsq, loffs, ssum, N, CAP);
    k_scan_sub      <<<1, 1024, 0, stream>>>(ssum, sbase, NS);
    k_csr_place     <<<NS, B, 0, stream>>>(gb, total, sbase, cnt, loffs, offs, csr, N, CAP);

    const int U16 = U * 16, I16 = I * 16, N16 = N * 16;
    k_init<<<(N16 + B - 1) / B, B, 0, stream>>>((const float4*)emb_u, (const float4*)emb_i,
                                                dinv, (ushort4*)g[0], U16, N16);

    for (int layer = 0; layer < 4; ++layer) {
        int threads = N * 8;               // 8 lanes per row
        k_layer<<<(threads + B - 1) / B, B, 0, stream>>>(
            (const uint4*)g[layer], (uint4*)g[layer + 1], dinv, offs, cnt, csr, N);
    }

    int totalv4 = 2 * U16 + 2 * I16;
    k_final<<<(totalv4 + B - 1) / B, B, 0, stream>>>(
        (const float4*)emb_u, (const float4*)emb_i,
        (const ushort4*)g[1], (const ushort4*)g[2], (const ushort4*)g[3], (const ushort4*)g[4],
        dsq, (float4*)d_out, U16, I16);
}

// Round 6
// 501.480 us; speedup vs baseline: 1.1746x; 1.1746x over previous
//
#include <hip/hip_runtime.h>

// LightGCN, atomic-free CSR build (bucketed counting sort) + bf16 g-form layers.
//
// Build pipeline (no global atomics, no memset), 256-node buckets (NB=586):
//   k_bucket_count   : 1024 blocks x disjoint edge ranges, LDS hist over
//                      node-buckets, dump bh[k][b].
//   k_scan_blocks    : per-bucket exclusive scan over the 1024 block counts
//                      (in-place in bh) + bucket totals.
//   k_scan_buckets   : exclusive scan of per-bucket ALLOC sizes
//                      (align4(total)+768) -> 4-entry-aligned bucket bases.
//   k_bucket_scatter : re-stream edge ranges; LDS-sort the block's entries
//                      by bucket (hist -> scan -> place w/ precomputed dst),
//                      stream out (sorted ~54B segments vs R2's random 8B).
//   k_csr_lds        : ONE 512-thread block per bucket: pass A reads staged
//                      entries (coalesced) -> LDS hist + float deg; 256-wide
//                      scan -> offs/cnt/dinv/dsq; pass B re-reads (L2-hot)
//                      placing entries INTO AN LDS IMAGE of the bucket's CSR
//                      (<=96KB); stream image out LINEARLY. Replaces R4's
//                      k_node_count/k_scan_sub/k_csr_place (150us: 16%
//                      occupancy cap + 93MB scattered-8B WRITE + 4x read
//                      amp). All scattered writes now terminate in LDS.
//
// g-form: g = dinv(*)e; s_r = sum v*g_c; g' = dinv_r^2 * s_r.
// k_final reconstructs acc = e0 + sum_l dsq*g_l (dsq = sqrt(deg)).
//
// k_layer (R2): GROUP-PER-ROW. 8 lanes per row (lane q holds dims 8q..8q+7
// as uint4), 8 rows per wave. No shuffles, no reduction epilogue. Inner
// loop: 2x dwordx4 csr loads + 4 independent 16B row gathers per 4
// neighbors, next csr block prefetched under the FMAs. Branch-free.

static inline size_t align_up(size_t x, size_t a) { return (x + a - 1) & ~(a - 1); }

#define NBA 640          // max buckets (N <= 163840); N = 150000 -> NB = 586
#define KB  1024         // edge-range blocks for count/scatter passes
#define ENT 4096         // staged entries per scatter block (2*CH <= 3908)
#define CAPL 12032       // LDS CSR-image entries (max bucket ~10.2K+17sig+pads)

__device__ inline unsigned short f32_to_bf16(float f) {
    unsigned int u = __float_as_uint(f);
    unsigned int r = (u + 0x7FFFu + ((u >> 16) & 1u)) >> 16;   // RNE
    return (unsigned short)r;
}
__device__ inline float bf16_to_f32(unsigned short h) {
    return __uint_as_float(((unsigned int)h) << 16);
}
__device__ inline float bf16_lo(unsigned int d) {
    return __uint_as_float(d << 16);
}
__device__ inline float bf16_hi(unsigned int d) {
    return __uint_as_float(d & 0xFFFF0000u);
}

// 1024 blocks, block k owns edges [k*CH, min(E,(k+1)*CH)).
// LDS histogram over node-buckets (node>>8); dump bh[k*NBA + b] (coalesced).
__global__ __launch_bounds__(256) void k_bucket_count(
        const int* __restrict__ eu, const int* __restrict__ ei,
        int* __restrict__ bh, int U, int E, int NB, int CH) {
    __shared__ int hist[NBA];
    int k = blockIdx.x;
    int t = threadIdx.x;
    for (int b = t; b < NBA; b += 256) hist[b] = 0;
    __syncthreads();
    int lo = k * CH, hi = min(E, lo + CH);
    for (int i = lo + t; i < hi; i += 256) {
        int u  = eu[i];
        int it = ei[i] + U;
        atomicAdd(&hist[u >> 8], 1);
        atomicAdd(&hist[it >> 8], 1);
    }
    __syncthreads();
    for (int b = t; b < NB; b += 256) bh[k * NBA + b] = hist[b];
}

// One block per bucket b: exclusive scan (in place) of bh[k][b] over k=0..1023,
// total[b] = sum. 256 threads x 4 sequential elements each.
__global__ __launch_bounds__(256) void k_scan_blocks(
        int* __restrict__ bh, int* __restrict__ total, int NB) {
    __shared__ int s[256];
    int b = blockIdx.x;
    int t = threadIdx.x;
    int k0 = t * 4;
    int vals[4];
    int sum = 0;
    #pragma unroll
    for (int j = 0; j < 4; ++j) { vals[j] = bh[(k0 + j) * NBA + b]; sum += vals[j]; }
    s[t] = sum;
    __syncthreads();
    for (int d = 1; d < 256; d <<= 1) {
        int v = (t >= d) ? s[t - d] : 0;
        __syncthreads();
        s[t] += v;
        __syncthreads();
    }
    int run = s[t] - sum;            // exclusive base for this thread's chunk
    #pragma unroll
    for (int j = 0; j < 4; ++j) { int v = vals[j]; bh[(k0 + j) * NBA + b] = run; run += v; }
    if (t == 255) total[b] = run;
}

// Single block: exclusive scan of per-bucket ALLOC sizes -> bucket CSR bases.
// alloc_b = align4(total_b) + 768 (worst-case per-node align4 padding for
// 256 nodes); all bases stay multiples of 4 entries (32B-aligned in csr).
__global__ __launch_bounds__(256) void k_scan_buckets(
        const int* __restrict__ total, int* __restrict__ bbase, int NB) {
    __shared__ int s[256];
    int t = threadIdx.x;
    int C = (NB + 255) / 256;        // <= 3 for NB <= 640 (vals[4] headroom)
    int vals[4];
    int sum = 0;
    for (int j = 0; j < C; ++j) {
        int idx = t * C + j;
        int v = (idx < NB) ? (((total[idx] + 3) & ~3) + 768) : 0;
        vals[j] = v; sum += v;
    }
    s[t] = sum;
    __syncthreads();
    for (int d = 1; d < 256; d <<= 1) {
        int v = (t >= d) ? s[t - d] : 0;
        __syncthreads();
        s[t] += v;
        __syncthreads();
    }
    int run = s[t] - sum;
    for (int j = 0; j < C; ++j) {
        int idx = t * C + j;
        if (idx < NB) bbase[idx] = run;
        run += vals[j];
    }
}

// LDS-sorted scatter. Entry: {(node&255) | (col<<8), v_bits} (26 bits).
// Phase 1: local hist over NB buckets. Phase 2: chunked (3/thread) scan ->
// segment starts + global-dst deltas. Phase 3: place entry + dst into LDS.
// Phase 4: stream out (consecutive threads -> consecutive slots of a
// bucket segment -> coalesced-ish ~54B runs).
__global__ __launch_bounds__(256) void k_bucket_scatter(
        const int* __restrict__ eu, const int* __restrict__ ei,
        const float* __restrict__ ev, const int* __restrict__ bh,
        int2* __restrict__ gb, int U, int E, int NB, int CH, int CAP) {
    __shared__ uint2 sent[ENT];
    __shared__ int   sdst[ENT];
    __shared__ int   lcur[NBA];
    __shared__ int   ldif[NBA];
    __shared__ int   sscan[256];
    int k = blockIdx.x;
    int t = threadIdx.x;
    for (int b = t; b < NBA; b += 256) lcur[b] = 0;
    __syncthreads();
    int lo = k * CH, hi = min(E, lo + CH);
    for (int i = lo + t; i < hi; i += 256) {
        int u  = eu[i];
        int it = ei[i] + U;
        atomicAdd(&lcur[u >> 8], 1);
        atomicAdd(&lcur[it >> 8], 1);
    }
    __syncthreads();
    // chunked scan over NB bins, 3 bins per thread
    int c3[3];
    int sum = 0;
    #pragma unroll
    for (int j = 0; j < 3; ++j) {
        int idx = t * 3 + j;
        int v = (idx < NB) ? lcur[idx] : 0;
        c3[j] = v; sum += v;
    }
    sscan[t] = sum;
    __syncthreads();
    for (int d = 1; d < 256; d <<= 1) {
        int v = (t >= d) ? sscan[t - d] : 0;
        __syncthreads();
        sscan[t] += v;
        __syncthreads();
    }
    int run = sscan[t] - sum;
    int tot = sscan[255];
    __syncthreads();
    #pragma unroll
    for (int j = 0; j < 3; ++j) {
        int idx = t * 3 + j;
        if (idx < NB) {
            lcur[idx] = run;                             // cursor = seg start
            ldif[idx] = idx * CAP + bh[k * NBA + idx] - run;
        }
        run += c3[j];
    }
    __syncthreads();
    for (int i = lo + t; i < hi; i += 256) {
        int u  = eu[i];
        int it = ei[i] + U;
        unsigned vb = __float_as_uint(ev[i]);
        int b1 = u >> 8;
        int s1 = atomicAdd(&lcur[b1], 1);
        sent[s1] = make_uint2((unsigned)((u & 255) | (it << 8)), vb);
        sdst[s1] = ldif[b1] + s1;
        int b2 = it >> 8;
        int s2 = atomicAdd(&lcur[b2], 1);
        sent[s2] = make_uint2((unsigned)((it & 255) | (u << 8)), vb);
        sdst[s2] = ldif[b2] + s2;
    }
    __syncthreads();
    for (int i = t; i < tot; i += 256) {
        uint2 e = sent[i];
        gb[sdst[i]] = make_int2((int)e.x, (int)e.y);
    }
}

// One 512-thread block per bucket. Pass A: staged entries -> LDS hist+deg.
// Scan 256 bins -> per-node padded offsets; write offs/cnt/dinv/dsq; zero
// pads in the LDS image. Pass B: re-read staged entries (L2-hot), place
// {col,v} into the LDS image. Stream image out linearly (coalesced).
__global__ __launch_bounds__(512) void k_csr_lds(
        const int2* __restrict__ gb, const int* __restrict__ total,
        const int* __restrict__ bbase,
        int* __restrict__ offs, int* __restrict__ cnt,
        float* __restrict__ dinv, float* __restrict__ dsq,
        int2* __restrict__ csr, int N, int CAP) {
    __shared__ int2  img[CAPL];
    __shared__ int   hist[256];
    __shared__ float degf[256];
    __shared__ int   lofs[256];
    __shared__ int   scan[256];
    __shared__ int   cur[256];
    int b = blockIdx.x;
    int t = threadIdx.x;
    int n0 = b << 8;
    int nbc = min(256, N - n0);
    int cb = min(total[b], CAP);
    int base = bbase[b];
    const int2* gbb = gb + (size_t)b * CAP;

    if (t < 256) { hist[t] = 0; degf[t] = 0.f; cur[t] = 0; }
    __syncthreads();
    for (int i = t; i < cb; i += 512) {
        int2 e = gbb[i];
        int rl = e.x & 255;
        atomicAdd(&hist[rl], 1);
        atomicAdd(&degf[rl], __int_as_float(e.y));
    }
    __syncthreads();
    int h = 0, h4 = 0;
    if (t < 256) {
        h = hist[t];
        h4 = (h + 3) & ~3;
        scan[t] = h4;
    }
    __syncthreads();
    for (int d = 1; d < 256; d <<= 1) {
        int v = (t >= d && t < 256) ? scan[t - d] : 0;
        __syncthreads();
        if (t < 256) scan[t] += v;
        __syncthreads();
    }
    int tpad = min(scan[255], CAPL);
    if (t < 256) {
        int off4 = scan[t] - h4;
        lofs[t] = off4;
        if (t < nbc) {
            int node = n0 + t;
            offs[node] = base + off4;
            cnt[node]  = h;
            float sd = degf[t];
            bool pos = (sd > 0.0f);
            dinv[node] = pos ? rsqrtf(fmaxf(sd, 1e-12f)) : 0.0f;
            dsq[node]  = pos ? sqrtf(sd) : 0.0f;
            for (int p = h; p < h4; ++p) {               // zero pad slots
                int ix = off4 + p;
                if (ix < CAPL) img[ix] = make_int2(0, 0);
            }
        }
    }
    __syncthreads();
    for (int i = t; i < cb; i += 512) {
        int2 e = gbb[i];
        int rl = e.x & 255;
        int tk = atomicAdd(&cur[rl], 1);
        int ix = lofs[rl] + tk;
        if (ix < CAPL)
            img[ix] = make_int2((int)(((unsigned)e.x) >> 8), e.y);
    }
    __syncthreads();
    for (int i = t; i < tpad; i += 512)
        csr[base + i] = img[i];
}

// g0 = bf16(dinv * concat(emb)). 4 elems/thread.
__global__ void k_init(const float4* __restrict__ emb_u, const float4* __restrict__ emb_i,
                       const float* __restrict__ dinv,
                       ushort4* __restrict__ g0, int U16, int N16) {
    int i = blockIdx.x * blockDim.x + threadIdx.x;
    if (i >= N16) return;
    float4 v = (i < U16) ? emb_u[i] : emb_i[i - U16];
    float d = dinv[i >> 4];
    ushort4 o;
    o.x = f32_to_bf16(v.x * d);
    o.y = f32_to_bf16(v.y * d);
    o.z = f32_to_bf16(v.z * d);
    o.w = f32_to_bf16(v.w * d);
    g0[i] = o;
}

// GROUP-PER-ROW: 8 lanes per row (q = lane&7 holds dims 8q..8q+7), 8 rows
// per wave. csr rows padded to 4-entry multiples, 32B-aligned -> inner loop
// is branch-free: 2x dwordx4 csr loads (broadcast within group) + 4
// independent 16B row gathers per 4 neighbors; next csr block prefetched
// under the FMAs. Pad entries {col=0,w=0} gather row 0 and add 0 (no-op).
__global__ __launch_bounds__(256) void k_layer(
        const uint4* __restrict__ gin, uint4* __restrict__ gout,
        const float* __restrict__ dinv,
        const int* __restrict__ offs, const int* __restrict__ cnt,
        const int2* __restrict__ csr, int N) {
    int gtid = blockIdx.x * blockDim.x + threadIdx.x;
    int row = gtid >> 3;
    unsigned q = threadIdx.x & 7;
    if (row >= N) return;
    int base = offs[row];
    int c = cnt[row];
    int nIter = (c + 3) >> 2;        // 4 neighbors per iteration

    float a0 = 0.f, a1 = 0.f, a2 = 0.f, a3 = 0.f;
    float a4 = 0.f, a5 = 0.f, a6 = 0.f, a7 = 0.f;

    const uint4* ep4 = (const uint4*)(csr + base);   // 32B-aligned
    uint4 E0 = make_uint4(0, 0, 0, 0), E1 = E0;
    if (nIter > 0) { E0 = ep4[0]; E1 = ep4[1]; }     // {c0,w0,c1,w1},{c2,w2,c3,w3}

    for (int i = 0; i < nIter; ++i) {
        uint4 G0 = gin[(E0.x << 3) | q];
        uint4 G1 = gin[(E0.z << 3) | q];
        uint4 G2 = gin[(E1.x << 3) | q];
        uint4 G3 = gin[(E1.z << 3) | q];
        // prefetch next csr block (reads <=32B past row end; slack allocated)
        uint4 P0 = ep4[2 * i + 2];
        uint4 P1 = ep4[2 * i + 3];
        float w0 = __uint_as_float(E0.y);
        float w1 = __uint_as_float(E0.w);
        float w2 = __uint_as_float(E1.y);
        float w3 = __uint_as_float(E1.w);
        a0 += w0 * bf16_lo(G0.x); a1 += w0 * bf16_hi(G0.x);
        a2 += w0 * bf16_lo(G0.y); a3 += w0 * bf16_hi(G0.y);
        a4 += w0 * bf16_lo(G0.z); a5 += w0 * bf16_hi(G0.z);
        a6 += w0 * bf16_lo(G0.w); a7 += w0 * bf16_hi(G0.w);
        a0 += w1 * bf16_lo(G1.x); a1 += w1 * bf16_hi(G1.x);
        a2 += w1 * bf16_lo(G1.y); a3 += w1 * bf16_hi(G1.y);
        a4 += w1 * bf16_lo(G1.z); a5 += w1 * bf16_hi(G1.z);
        a6 += w1 * bf16_lo(G1.w); a7 += w1 * bf16_hi(G1.w);
        a0 += w2 * bf16_lo(G2.x); a1 += w2 * bf16_hi(G2.x);
        a2 += w2 * bf16_lo(G2.y); a3 += w2 * bf16_hi(G2.y);
        a4 += w2 * bf16_lo(G2.z); a5 += w2 * bf16_hi(G2.z);
        a6 += w2 * bf16_lo(G2.w); a7 += w2 * bf16_hi(G2.w);
        a0 += w3 * bf16_lo(G3.x); a1 += w3 * bf16_hi(G3.x);
        a2 += w3 * bf16_lo(G3.y); a3 += w3 * bf16_hi(G3.y);
        a4 += w3 * bf16_lo(G3.z); a5 += w3 * bf16_hi(G3.z);
        a6 += w3 * bf16_lo(G3.w); a7 += w3 * bf16_hi(G3.w);
        E0 = P0; E1 = P1;
    }

    float dr = dinv[row];
    float d2 = dr * dr;
    uint4 o;
    o.x = (unsigned int)f32_to_bf16(d2 * a0) | ((unsigned int)f32_to_bf16(d2 * a1) << 16);
    o.y = (unsigned int)f32_to_bf16(d2 * a2) | ((unsigned int)f32_to_bf16(d2 * a3) << 16);
    o.z = (unsigned int)f32_to_bf16(d2 * a4) | ((unsigned int)f32_to_bf16(d2 * a5) << 16);
    o.w = (unsigned int)f32_to_bf16(d2 * a6) | ((unsigned int)f32_to_bf16(d2 * a7) << 16);
    gout[((unsigned)row << 3) | q] = o;
}

// out (float4 units): [Uf | Upass | If | Ipass]; Uf/If = (e0 + sum dsq*g_l)/25.
__global__ void k_final(const float4* __restrict__ emb_u, const float4* __restrict__ emb_i,
                        const ushort4* __restrict__ g1, const ushort4* __restrict__ g2,
                        const ushort4* __restrict__ g3, const ushort4* __restrict__ g4,
                        const float* __restrict__ dsq,
                        float4* __restrict__ out, int U16, int I16) {
    int i = blockIdx.x * blockDim.x + threadIdx.x;
    int total = 2 * U16 + 2 * I16;
    if (i >= total) return;
    const float s = 1.0f / 25.0f;
    float4 r;
    if (i < U16 || (i >= 2 * U16 && i < 2 * U16 + I16)) {
        int gi, node;
        float4 e0;
        if (i < U16) { gi = i; node = i >> 4; e0 = emb_u[i]; }
        else { int j = i - 2 * U16; gi = U16 + j; node = (U16 >> 4) + (j >> 4); e0 = emb_i[j]; }
        float d = dsq[node];
        ushort4 a = g1[gi], b = g2[gi], cc = g3[gi], dd = g4[gi];
        float gx = bf16_to_f32(a.x) + bf16_to_f32(b.x) + bf16_to_f32(cc.x) + bf16_to_f32(dd.x);
        float gy = bf16_to_f32(a.y) + bf16_to_f32(b.y) + bf16_to_f32(cc.y) + bf16_to_f32(dd.y);
        float gz = bf16_to_f32(a.z) + bf16_to_f32(b.z) + bf16_to_f32(cc.z) + bf16_to_f32(dd.z);
        float gw = bf16_to_f32(a.w) + bf16_to_f32(b.w) + bf16_to_f32(cc.w) + bf16_to_f32(dd.w);
        r = make_float4((e0.x + d * gx) * s, (e0.y + d * gy) * s,
                        (e0.z + d * gz) * s, (e0.w + d * gw) * s);
    } else if (i < 2 * U16) {
        r = emb_u[i - U16];
    } else {
        r = emb_i[i - 2 * U16 - I16];
    }
    out[i] = r;
}

extern "C" void kernel_launch(void* const* d_in, const int* in_sizes, int n_in,
                              void* d_out, int out_size, void* d_ws, size_t ws_size,
                              hipStream_t stream) {
    const float* emb_u = (const float*)d_in[0];
    const float* emb_i = (const float*)d_in[1];
    const int*   eu    = (const int*)d_in[2];
    const int*   ei    = (const int*)d_in[3];
    const float* ev    = (const float*)d_in[4];

    const int U = in_sizes[0] / 64;
    const int I = in_sizes[1] / 64;
    const int N = U + I;
    const int E = in_sizes[2];
    const int DE = 2 * E;

    const int NB = (N + 255) >> 8;         // 586 buckets for N = 150000 (<= NBA)
    const int CH = (E + KB - 1) / KB;      // edges per count/scatter block

    // ---- workspace carve ----
    char* base = (char*)d_ws;
    size_t off = 0;
    int*   offs  = (int*)  (base + off); off = align_up(off + (size_t)N * 4, 256);
    int*   cnt   = (int*)  (base + off); off = align_up(off + (size_t)N * 4, 256);
    float* dinv  = (float*)(base + off); off = align_up(off + (size_t)N * 4, 256);
    float* dsq   = (float*)(base + off); off = align_up(off + (size_t)N * 4, 256);
    int*   bh    = (int*)  (base + off); off = align_up(off + (size_t)NBA * KB * 4, 256);
    int*   total = (int*)  (base + off); off = align_up(off + (size_t)NBA * 4, 256);
    int*   bbase = (int*)  (base + off); off = align_up(off + (size_t)NBA * 4, 256);
    // padded CSR: DE entries + per-bucket (align4 + 768) slack + prefetch slack
    int2*  csr   = (int2*) (base + off);
    off = align_up(off + ((size_t)DE + (size_t)NBA * 772 + 32) * 8, 256);
    unsigned short* g[5];
    for (int l = 0; l < 5; ++l) {
        g[l] = (unsigned short*)(base + off);
        off = align_up(off + (size_t)N * 64 * 2, 256);
    }
    (void)ws_size;

    // Bucket staging aliases g[1..4] (dead until layer 0 writes g[1]).
    int2* gb = (int2*)g[1];
    size_t gcap = (size_t)4 * N * 128;                 // bytes available at g[1]
    int CAP = (int)(gcap / ((size_t)NB * 8));          // per-bucket entry cap
    if (CAP > 16128) CAP = 16128;                      // ~1.5x max expected bucket load

    const int B = 256;
    k_bucket_count  <<<KB, B, 0, stream>>>(eu, ei, bh, U, E, NB, CH);
    k_scan_blocks   <<<NB, B, 0, stream>>>(bh, total, NB);
    k_scan_buckets  <<<1,  B, 0, stream>>>(total, bbase, NB);
    k_bucket_scatter<<<KB, B, 0, stream>>>(eu, ei, ev, bh, gb, U, E, NB, CH, CAP);
    k_csr_lds       <<<NB, 512, 0, stream>>>(gb, total, bbase, offs, cnt, dinv, dsq, csr, N, CAP);

    const int U16 = U * 16, I16 = I * 16, N16 = N * 16;
    k_init<<<(N16 + B - 1) / B, B, 0, stream>>>((const float4*)emb_u, (const float4*)emb_i,
                                                dinv, (ushort4*)g[0], U16, N16);

    for (int layer = 0; layer < 4; ++layer) {
        int threads = N * 8;               // 8 lanes per row
        k_layer<<<(threads + B - 1) / B, B, 0, stream>>>(
            (const uint4*)g[layer], (uint4*)g[layer + 1], dinv, offs, cnt, csr, N);
    }

    int totalv4 = 2 * U16 + 2 * I16;
    k_final<<<(totalv4 + B - 1) / B, B, 0, stream>>>(
        (const float4*)emb_u, (const float4*)emb_i,
        (const ushort4*)g[1], (const ushort4*)g[2], (const ushort4*)g[3], (const ushort4*)g[4],
        dsq, (float4*)d_out, U16, I16);
}